// Round 1
// baseline (1722.874 us; speedup 1.0000x reference)
//
#include <hip/hip_runtime.h>

#define EPB 32
#define THREADS 256

__device__ __forceinline__ float sigmoidf_(float v) { return 1.f / (1.f + expf(-v)); }

struct EdgeLds {
    float rad[EPB][8];
    float yM[EPB][16];   // [0]=y0, [1..3]=y1, [4+3i+k]=M[i][k]
    int   src[EPB];
    float h[EPB][68];    // padded stride 68 -> conflict-free b128 reads
    float t00[EPB][32];
    float t11[EPB][32];
    float t01[EPB][96];  // [3u+k]
    float t10[EPB][96];
    float t12[EPB][96];
};

__global__ __launch_bounds__(THREADS, 2)
void edge_kernel(const float* __restrict__ x, const float* __restrict__ ea,
                 const float* __restrict__ elen, const int* __restrict__ esrc,
                 const int* __restrict__ edst, const float* __restrict__ W1,
                 const float* __restrict__ W2, float* __restrict__ sums,
                 float* __restrict__ cnt, int N, int E)
{
    __shared__ EdgeLds S;
    const int tid = threadIdx.x;
    const int e0 = blockIdx.x * EPB;

    // ---- phase 1a: per-edge scalars: radial basis, y, M matrix ----
    for (int i = tid; i < EPB; i += THREADS) {
        int e = e0 + i;
        if (e < E) {
            float L = elen[e];
#pragma unroll
            for (int r = 0; r < 8; ++r) {
                float d = L - (float)r * (5.f / 7.f);
                S.rad[i][r] = expf(-d * d * 0.98f);   // 1/(2*sigma^2)=49/50
            }
            const float* y = ea + (size_t)e * 9;
            float y0 = y[0], ya = y[1], yb = y[2], yc = y[3];
            float a = y[4], b = y[5], c = y[6], d2 = y[7], ee = y[8];
            S.yM[i][0] = y0; S.yM[i][1] = ya; S.yM[i][2] = yb; S.yM[i][3] = yc;
            const float I5 = 0.4472135955f, S2 = 0.7071067812f;
            const float I6 = 0.4082482905f, T6 = 0.8164965809f;
            S.yM[i][4 + 0] = (-c * I6 + ee * S2) * I5;  // M[0][0]
            S.yM[i][4 + 1] = a * S2 * I5;               // M[0][1]
            S.yM[i][4 + 2] = d2 * S2 * I5;              // M[0][2]
            S.yM[i][4 + 3] = a * S2 * I5;               // M[1][0]
            S.yM[i][4 + 4] = (-c * I6 - ee * S2) * I5;  // M[1][1]
            S.yM[i][4 + 5] = b * S2 * I5;               // M[1][2]
            S.yM[i][4 + 6] = d2 * S2 * I5;              // M[2][0]
            S.yM[i][4 + 7] = b * S2 * I5;               // M[2][1]
            S.yM[i][4 + 8] = c * T6 * I5;               // M[2][2]
            S.src[i] = esrc[e];
        }
    }
    __syncthreads();

    // ---- phase 1b: h = silu(radial @ W1/sqrt(8)) * 1/8  (folds W_fc2/8) ----
    for (int idx = tid; idx < EPB * 64; idx += THREADS) {
        int i = idx >> 6, c = idx & 63;
        if (e0 + i < E) {
            float d = 0.f;
#pragma unroll
            for (int r = 0; r < 8; ++r) d += S.rad[i][r] * W1[r * 64 + c];
            d *= 0.3535533906f;                 // 1/sqrt(8)
            float h = d * sigmoidf_(d);         // silu
            S.h[i][c] = h * 0.125f;             // 1/sqrt(64)
        } else {
            S.h[i][c] = 0.f;
        }
    }

    // ---- phase 1c: t tensors ----
    for (int idx = tid; idx < EPB * 32; idx += THREADS) {
        int i = idx >> 5, u = idx & 31;
        if (e0 + i < E) {
            const float* xp = x + (size_t)S.src[i] * 128;
            float s  = xp[u];
            float v0 = xp[32 + 3 * u], v1 = xp[33 + 3 * u], v2 = xp[34 + 3 * u];
            float y0 = S.yM[i][0], ya = S.yM[i][1], yb = S.yM[i][2], yc = S.yM[i][3];
            const float I3 = 0.5773502692f;
            S.t00[i][u] = s * y0;
            S.t11[i][u] = (v0 * ya + v1 * yb + v2 * yc) * I3;
            S.t01[i][3 * u + 0] = s * ya * I3;
            S.t01[i][3 * u + 1] = s * yb * I3;
            S.t01[i][3 * u + 2] = s * yc * I3;
            S.t10[i][3 * u + 0] = v0 * y0 * I3;
            S.t10[i][3 * u + 1] = v1 * y0 * I3;
            S.t10[i][3 * u + 2] = v2 * y0 * I3;
#pragma unroll
            for (int k = 0; k < 3; ++k)
                S.t12[i][3 * u + k] = v0 * S.yM[i][4 + k] + v1 * S.yM[i][4 + 3 + k] + v2 * S.yM[i][4 + 6 + k];
        }
    }
    __syncthreads();

    // ---- main: fused w-matvec + t-fold ----
    const int wq = tid & 7;    // w-quad: w = 4*wq + j
    const int es = tid >> 3;   // edge slot 0..31
    const int e  = e0 + es;
    float accS[4] = {0, 0, 0, 0};
    float accG[4] = {0, 0, 0, 0};
    float accV[3][4] = {{0, 0, 0, 0}, {0, 0, 0, 0}, {0, 0, 0, 0}};
    const float* W2q  = W2 + (wq << 2);
    const float* hrow = S.h[es];

    for (int p = 0; p < 7; ++p) {
        for (int u = 0; u < 32; ++u) {
            const float* Wpu = W2q + (p * 1024 + u * 32);
            float4 wa = make_float4(0.f, 0.f, 0.f, 0.f);
#pragma unroll 4
            for (int cq = 0; cq < 16; ++cq) {
                const float4 hq = *(const float4*)(hrow + (cq << 2));
                const float* wp = Wpu + (size_t)(cq << 2) * 7168;
                const float4 a0 = *(const float4*)(wp);
                const float4 a1 = *(const float4*)(wp + 7168);
                const float4 a2 = *(const float4*)(wp + 2 * 7168);
                const float4 a3 = *(const float4*)(wp + 3 * 7168);
                wa.x += hq.x * a0.x; wa.y += hq.x * a0.y; wa.z += hq.x * a0.z; wa.w += hq.x * a0.w;
                wa.x += hq.y * a1.x; wa.y += hq.y * a1.y; wa.z += hq.y * a1.z; wa.w += hq.y * a1.w;
                wa.x += hq.z * a2.x; wa.y += hq.z * a2.y; wa.z += hq.z * a2.z; wa.w += hq.z * a2.w;
                wa.x += hq.w * a3.x; wa.y += hq.w * a3.y; wa.z += hq.w * a3.z; wa.w += hq.w * a3.w;
            }
            if (p < 2) {
                float t = (p & 1) ? S.t11[es][u] : S.t00[es][u];
                accS[0] += t * wa.x; accS[1] += t * wa.y; accS[2] += t * wa.z; accS[3] += t * wa.w;
            } else if (p < 4) {
                float t = (p & 1) ? S.t11[es][u] : S.t00[es][u];
                accG[0] += t * wa.x; accG[1] += t * wa.y; accG[2] += t * wa.z; accG[3] += t * wa.w;
            } else {
                const float* tp = (p == 4) ? &S.t01[es][3 * u]
                                : (p == 5) ? &S.t10[es][3 * u]
                                           : &S.t12[es][3 * u];
#pragma unroll
                for (int k = 0; k < 3; ++k) {
                    float t = tp[k];
                    accV[k][0] += t * wa.x; accV[k][1] += t * wa.y;
                    accV[k][2] += t * wa.z; accV[k][3] += t * wa.w;
                }
            }
        }
    }

    if (e < E) {
        const int dst = edst[e];
        float* sp = sums + (size_t)dst * 160;
        const float A0 = 0.125f;          // 1/sqrt(64)
        const float A1 = 0.1767766953f;   // sqrt(3/96)
#pragma unroll
        for (int j = 0; j < 4; ++j) {
            int w = (wq << 2) + j;
            atomicAdd(&sp[w],            accS[j] * A0);
            atomicAdd(&sp[32 + w],       accG[j] * A0);
            atomicAdd(&sp[64 + 3 * w + 0], accV[0][j] * A1);
            atomicAdd(&sp[64 + 3 * w + 1], accV[1][j] * A1);
            atomicAdd(&sp[64 + 3 * w + 2], accV[2][j] * A1);
        }
        if (wq == 0) atomicAdd(&cnt[dst], 1.0f);
    }
}

__global__ __launch_bounds__(256)
void node_kernel(const float* __restrict__ x, const float* __restrict__ Wss,
                 const float* __restrict__ Wsv, const float* __restrict__ sums,
                 const float* __restrict__ cnt, float* __restrict__ out, int N)
{
    int t = blockIdx.x * 256 + threadIdx.x;
    int n = t >> 6, col = t & 63;
    if (n >= N) return;
    const float inv_c = 1.f / fmaxf(cnt[n], 1.f);
    const float* m  = sums + (size_t)n * 160;
    const float* xp = x + (size_t)n * 128;
    const float IM = 0.1767766953f;  // 1/sqrt(32)
    if (col < 32) {
        int w = col;
        float ms = m[w] * inv_c;
        float gs = ms * sigmoidf_(ms);
        float dot = 0.f;
#pragma unroll 4
        for (int u = 0; u < 32; ++u) dot += xp[u] * Wss[u * 32 + w];
        float hs = gs + dot * IM;
        out[(size_t)n * 64 + w] = sqrtf(hs * hs + 1e-12f);
    } else {
        int w = col - 32;
        float gate = sigmoidf_(m[32 + w] * inv_c);
        float g0 = m[64 + 3 * w + 0] * inv_c * gate;
        float g1 = m[64 + 3 * w + 1] * inv_c * gate;
        float g2 = m[64 + 3 * w + 2] * inv_c * gate;
        float d0 = 0.f, d1 = 0.f, d2 = 0.f;
#pragma unroll 4
        for (int u = 0; u < 32; ++u) {
            float wv = Wsv[u * 32 + w];
            d0 += xp[32 + 3 * u + 0] * wv;
            d1 += xp[32 + 3 * u + 1] * wv;
            d2 += xp[32 + 3 * u + 2] * wv;
        }
        float h0 = g0 + d0 * IM, h1 = g1 + d1 * IM, h2 = g2 + d2 * IM;
        out[(size_t)n * 64 + 32 + w] = sqrtf(h0 * h0 + h1 * h1 + h2 * h2 + 1e-12f);
    }
}

extern "C" void kernel_launch(void* const* d_in, const int* in_sizes, int n_in,
                              void* d_out, int out_size, void* d_ws, size_t ws_size,
                              hipStream_t stream)
{
    const float* x    = (const float*)d_in[0];
    const float* ea   = (const float*)d_in[1];
    const float* elen = (const float*)d_in[2];
    const int*   esrc = (const int*)d_in[3];
    const int*   edst = (const int*)d_in[4];
    const float* W1   = (const float*)d_in[5];
    const float* W2   = (const float*)d_in[6];
    const float* Wss  = (const float*)d_in[7];
    const float* Wsv  = (const float*)d_in[8];
    float* out = (float*)d_out;

    const int N = in_sizes[0] / 128;   // 4096
    const int E = in_sizes[2];         // 32768

    float* sums = (float*)d_ws;                  // N*160
    float* cnt  = sums + (size_t)N * 160;        // N

    hipMemsetAsync(d_ws, 0, (size_t)N * 161 * sizeof(float), stream);

    const int gridE = (E + EPB - 1) / EPB;
    edge_kernel<<<gridE, THREADS, 0, stream>>>(x, ea, elen, esrc, edst, W1, W2, sums, cnt, N, E);

    const int gridN = (N * 64 + 255) / 256;
    node_kernel<<<gridN, 256, 0, stream>>>(x, Wss, Wsv, sums, cnt, out, N);
}

// Round 2
// 524.778 us; speedup vs baseline: 3.2831x; 3.2831x over previous
//
#include <hip/hip_runtime.h>

#define NKNOT 257          // 256 intervals over [0,5]
#define KINV  51.2f        // 256/5
#define KSTEP 0.01953125f  // 5/256 (exact in fp32)
#define TPW   7168

__device__ __forceinline__ float sigmoidf_(float v) { return 1.f / (1.f + expf(-v)); }

// ---------------- h(L_k) knot table: hk[NKNOT][64] ----------------
__global__ void hk_kernel(const float* __restrict__ W1, float* __restrict__ hk)
{
    int idx = blockIdx.x * 256 + threadIdx.x;
    if (idx >= NKNOT * 64) return;
    int k = idx >> 6, c = idx & 63;
    float L = (float)k * KSTEP;
    float d = 0.f;
#pragma unroll
    for (int r = 0; r < 8; ++r) {
        float dd = L - (float)r * (5.f / 7.f);
        d += expf(-dd * dd * 0.98f) * W1[r * 64 + c];
    }
    d *= 0.3535533906f;                 // 1/sqrt(8)
    hk[idx] = d * sigmoidf_(d) * 0.125f; // silu, then 1/sqrt(64)
}

// ---------------- T[k][pw] = hk[k] @ W2 ----------------
__global__ __launch_bounds__(256)
void table_kernel(const float* __restrict__ hk, const float* __restrict__ W2,
                  float* __restrict__ T)
{
    int pw = blockIdx.x * 1024 + threadIdx.x * 4;
    int kt = blockIdx.y * 8;
    float4 acc[8];
#pragma unroll
    for (int q = 0; q < 8; ++q) acc[q] = make_float4(0.f, 0.f, 0.f, 0.f);
    for (int c = 0; c < 64; ++c) {
        float4 w4 = *(const float4*)(W2 + (size_t)c * TPW + pw);
#pragma unroll
        for (int q = 0; q < 8; ++q) {
            int kk = kt + q; kk = kk < NKNOT ? kk : NKNOT - 1;
            float hv = hk[kk * 64 + c];   // uniform -> scalar load
            acc[q].x = fmaf(hv, w4.x, acc[q].x);
            acc[q].y = fmaf(hv, w4.y, acc[q].y);
            acc[q].z = fmaf(hv, w4.z, acc[q].z);
            acc[q].w = fmaf(hv, w4.w, acc[q].w);
        }
    }
#pragma unroll
    for (int q = 0; q < 8; ++q)
        if (kt + q < NKNOT)
            *(float4*)(T + (size_t)(kt + q) * TPW + pw) = acc[q];
}

// ---------------- counting sort by interval ----------------
__global__ void hist_kernel(const float* __restrict__ elen, int* __restrict__ histL, int E)
{
    int e = blockIdx.x * 256 + threadIdx.x;
    if (e >= E) return;
    float t = elen[e] * KINV;
    int j = (int)t; j = j > 255 ? 255 : j;
    atomicAdd(&histL[j], 1);
}

__global__ void scan_kernel(const int* __restrict__ histL, int* __restrict__ offL,
                            int* __restrict__ curL)
{
    __shared__ int sbuf[256];
    int t = threadIdx.x;
    int v = histL[t];
    sbuf[t] = v;
    __syncthreads();
    for (int d = 1; d < 256; d <<= 1) {
        int w = (t >= d) ? sbuf[t - d] : 0;
        __syncthreads();
        sbuf[t] += w;
        __syncthreads();
    }
    offL[t + 1] = sbuf[t];
    curL[t] = sbuf[t] - v;   // exclusive
    if (t == 0) offL[0] = 0;
}

__global__ void scatter_kernel(const float* __restrict__ elen, int* __restrict__ curL,
                               int* __restrict__ sortedL, int E)
{
    int e = blockIdx.x * 256 + threadIdx.x;
    if (e >= E) return;
    float t = elen[e] * KINV;
    int j = (int)t; j = j > 255 ? 255 : j;
    int pos = atomicAdd(&curL[j], 1);
    sortedL[pos] = e;
}

// ---------------- main fold kernel ----------------
// grid = 512 blocks: (interval = bid>>1, half = bid&1). 256 threads =
// 32 slots x 8 w-quads; each slot processes 2 edges per 64-edge chunk
// (register reuse of the T rows across the edge pair).
__global__ __launch_bounds__(256, 2)
void fold_kernel(const float* __restrict__ x, const float* __restrict__ ea,
                 const float* __restrict__ elen, const int* __restrict__ esrc,
                 const int* __restrict__ edst, const int* __restrict__ offL,
                 const int* __restrict__ sortedL, const float* __restrict__ T,
                 float* __restrict__ sums, float* __restrict__ cnt)
{
    const int j = blockIdx.x >> 1, half = blockIdx.x & 1;
    __shared__ float Tj[TPW];
    __shared__ float Tj1[TPW];
    __shared__ float EC[64][20];
    const int tid = threadIdx.x;

    // stage the two table rows
    const float* Trow = T + (size_t)j * TPW;
    for (int i = tid; i < TPW / 4; i += 256) {
        ((float4*)Tj)[i]  = ((const float4*)Trow)[i];
        ((float4*)Tj1)[i] = ((const float4*)(Trow + TPW))[i];
    }

    const int lo = offL[j], hi = offL[j + 1];
    const int nchunk = (hi - lo + 63) >> 6;
    const int slot = tid >> 3, wq = tid & 7;
    const float4* T4a = (const float4*)Tj;
    const float4* T4b = (const float4*)Tj1;
    const float I3 = 0.5773502692f, I5 = 0.4472135955f, S2 = 0.7071067812f;
    const float I6 = 0.4082482905f, T6 = 0.8164965809f;
    const float A0 = 0.125f, A1 = 0.1767766953f;

    for (int ci = half; ci < nchunk; ci += 2) {
        const int base = lo + (ci << 6);
        const int cntE = min(64, hi - base);
        __syncthreads();   // T ready (iter 0); EC free (later iters)
        if (tid < 64 && tid < cntE) {
            int e = sortedL[base + tid];
            float L = elen[e];
            float t = L * KINV;
            int jj = (int)t; jj = jj > 255 ? 255 : jj;
            EC[tid][0] = t - (float)jj;
            EC[tid][1] = __int_as_float(esrc[e]);
            EC[tid][2] = __int_as_float(edst[e]);
            const float* y = ea + (size_t)e * 9;
            float y0 = y[0];
            EC[tid][3] = y0;
            EC[tid][4] = y0 * I3;
            EC[tid][5] = y[1] * I3;
            EC[tid][6] = y[2] * I3;
            EC[tid][7] = y[3] * I3;
            float a = y[4], b = y[5], c = y[6], d2 = y[7], ee = y[8];
            EC[tid][8]  = (-c * I6 + ee * S2) * I5;
            EC[tid][9]  = a * S2 * I5;
            EC[tid][10] = d2 * S2 * I5;
            EC[tid][11] = a * S2 * I5;
            EC[tid][12] = (-c * I6 - ee * S2) * I5;
            EC[tid][13] = b * S2 * I5;
            EC[tid][14] = d2 * S2 * I5;
            EC[tid][15] = b * S2 * I5;
            EC[tid][16] = c * T6 * I5;
        }
        __syncthreads();

        const bool okA = slot < cntE;
        const bool okB = slot + 32 < cntE;
        float fA = EC[slot][0],      fB = EC[slot + 32][0];
        int srcA = okA ? __float_as_int(EC[slot][1]) : 0;
        int srcB = okB ? __float_as_int(EC[slot + 32][1]) : 0;
        int dstA = okA ? __float_as_int(EC[slot][2]) : 0;
        int dstB = okB ? __float_as_int(EC[slot + 32][2]) : 0;
        float y0A = EC[slot][3],  y0iA = EC[slot][4];
        float y0B = EC[slot + 32][3], y0iB = EC[slot + 32][4];
        float y1iA[3] = { EC[slot][5], EC[slot][6], EC[slot][7] };
        float y1iB[3] = { EC[slot + 32][5], EC[slot + 32][6], EC[slot + 32][7] };
        float MA[9], MB[9];
#pragma unroll
        for (int q = 0; q < 9; ++q) { MA[q] = EC[slot][8 + q]; MB[q] = EC[slot + 32][8 + q]; }

        float accA[20], accB[20];
#pragma unroll
        for (int q = 0; q < 20; ++q) { accA[q] = 0.f; accB[q] = 0.f; }

        const float* xA = x + (size_t)srcA * 128;
        const float* xB = x + (size_t)srcB * 128;

#pragma unroll 1
        for (int uq = 0; uq < 8; ++uq) {
            float s4A[4], s4B[4], vvA[12], vvB[12];
            *(float4*)s4A = *(const float4*)(xA + (uq << 2));
            *(float4*)s4B = *(const float4*)(xB + (uq << 2));
            *(float4*)(vvA)     = *(const float4*)(xA + 32 + 12 * uq);
            *(float4*)(vvA + 4) = *(const float4*)(xA + 36 + 12 * uq);
            *(float4*)(vvA + 8) = *(const float4*)(xA + 40 + 12 * uq);
            *(float4*)(vvB)     = *(const float4*)(xB + 32 + 12 * uq);
            *(float4*)(vvB + 4) = *(const float4*)(xB + 36 + 12 * uq);
            *(float4*)(vvB + 8) = *(const float4*)(xB + 40 + 12 * uq);
#pragma unroll
            for (int up = 0; up < 4; ++up) {
                const int u = (uq << 2) + up;
                const float sA = s4A[up], sB = s4B[up];
                const float* vA_ = vvA + 3 * up;
                const float* vB_ = vvB + 3 * up;
                float t00A = sA * y0A;
                float t00B = sB * y0B;
                float t11A = vA_[0] * y1iA[0] + vA_[1] * y1iA[1] + vA_[2] * y1iA[2];
                float t11B = vB_[0] * y1iB[0] + vB_[1] * y1iB[1] + vB_[2] * y1iB[2];
                float t01A[3], t01B[3], t10A[3], t10B[3], t12A[3], t12B[3];
#pragma unroll
                for (int k = 0; k < 3; ++k) {
                    t01A[k] = sA * y1iA[k];
                    t01B[k] = sB * y1iB[k];
                    t10A[k] = vA_[k] * y0iA;
                    t10B[k] = vB_[k] * y0iB;
                    t12A[k] = vA_[0] * MA[k] + vA_[1] * MA[3 + k] + vA_[2] * MA[6 + k];
                    t12B[k] = vB_[0] * MB[k] + vB_[1] * MB[3 + k] + vB_[2] * MB[6 + k];
                }
                const int pw4 = (u << 3) + wq;
#pragma unroll
                for (int p = 0; p < 7; ++p) {
                    float4 Ta = T4a[(p << 8) + pw4];
                    float4 Tb = T4b[(p << 8) + pw4];
                    float d0 = Tb.x - Ta.x, d1 = Tb.y - Ta.y, d2_ = Tb.z - Ta.z, d3 = Tb.w - Ta.w;
                    float a0 = fmaf(fA, d0, Ta.x), a1 = fmaf(fA, d1, Ta.y);
                    float a2 = fmaf(fA, d2_, Ta.z), a3 = fmaf(fA, d3, Ta.w);
                    float b0 = fmaf(fB, d0, Ta.x), b1 = fmaf(fB, d1, Ta.y);
                    float b2 = fmaf(fB, d2_, Ta.z), b3 = fmaf(fB, d3, Ta.w);
                    if (p < 4) {
                        const int off = (p >> 1) << 2;   // 0 (S) or 4 (G)
                        float tA = (p & 1) ? t11A : t00A;
                        float tB = (p & 1) ? t11B : t00B;
                        accA[off + 0] = fmaf(tA, a0, accA[off + 0]);
                        accA[off + 1] = fmaf(tA, a1, accA[off + 1]);
                        accA[off + 2] = fmaf(tA, a2, accA[off + 2]);
                        accA[off + 3] = fmaf(tA, a3, accA[off + 3]);
                        accB[off + 0] = fmaf(tB, b0, accB[off + 0]);
                        accB[off + 1] = fmaf(tB, b1, accB[off + 1]);
                        accB[off + 2] = fmaf(tB, b2, accB[off + 2]);
                        accB[off + 3] = fmaf(tB, b3, accB[off + 3]);
                    } else {
#pragma unroll
                        for (int k = 0; k < 3; ++k) {
                            float tA = (p == 4) ? t01A[k] : (p == 5) ? t10A[k] : t12A[k];
                            float tB = (p == 4) ? t01B[k] : (p == 5) ? t10B[k] : t12B[k];
                            const int off = 8 + (k << 2);
                            accA[off + 0] = fmaf(tA, a0, accA[off + 0]);
                            accA[off + 1] = fmaf(tA, a1, accA[off + 1]);
                            accA[off + 2] = fmaf(tA, a2, accA[off + 2]);
                            accA[off + 3] = fmaf(tA, a3, accA[off + 3]);
                            accB[off + 0] = fmaf(tB, b0, accB[off + 0]);
                            accB[off + 1] = fmaf(tB, b1, accB[off + 1]);
                            accB[off + 2] = fmaf(tB, b2, accB[off + 2]);
                            accB[off + 3] = fmaf(tB, b3, accB[off + 3]);
                        }
                    }
                }
            }
        }

        const int wbase = wq << 2;
        if (okA) {
            float* sp = sums + (size_t)dstA * 160;
#pragma unroll
            for (int jj = 0; jj < 4; ++jj) {
                int w = wbase + jj;
                atomicAdd(sp + w,                accA[jj] * A0);
                atomicAdd(sp + 32 + w,           accA[4 + jj] * A0);
                atomicAdd(sp + 64 + 3 * w + 0,   accA[8 + jj] * A1);
                atomicAdd(sp + 64 + 3 * w + 1,   accA[12 + jj] * A1);
                atomicAdd(sp + 64 + 3 * w + 2,   accA[16 + jj] * A1);
            }
            if (wq == 0) atomicAdd(&cnt[dstA], 1.0f);
        }
        if (okB) {
            float* sp = sums + (size_t)dstB * 160;
#pragma unroll
            for (int jj = 0; jj < 4; ++jj) {
                int w = wbase + jj;
                atomicAdd(sp + w,                accB[jj] * A0);
                atomicAdd(sp + 32 + w,           accB[4 + jj] * A0);
                atomicAdd(sp + 64 + 3 * w + 0,   accB[8 + jj] * A1);
                atomicAdd(sp + 64 + 3 * w + 1,   accB[12 + jj] * A1);
                atomicAdd(sp + 64 + 3 * w + 2,   accB[16 + jj] * A1);
            }
            if (wq == 0) atomicAdd(&cnt[dstB], 1.0f);
        }
    }
}

// ---------------- per-node epilogue ----------------
__global__ __launch_bounds__(256)
void node_kernel(const float* __restrict__ x, const float* __restrict__ Wss,
                 const float* __restrict__ Wsv, const float* __restrict__ sums,
                 const float* __restrict__ cnt, float* __restrict__ out, int N)
{
    int t = blockIdx.x * 256 + threadIdx.x;
    int n = t >> 6, col = t & 63;
    if (n >= N) return;
    const float inv_c = 1.f / fmaxf(cnt[n], 1.f);
    const float* m  = sums + (size_t)n * 160;
    const float* xp = x + (size_t)n * 128;
    const float IM = 0.1767766953f;  // 1/sqrt(32)
    if (col < 32) {
        int w = col;
        float ms = m[w] * inv_c;
        float gs = ms * sigmoidf_(ms);
        float dot = 0.f;
#pragma unroll 4
        for (int u = 0; u < 32; ++u) dot += xp[u] * Wss[u * 32 + w];
        float hs = gs + dot * IM;
        out[(size_t)n * 64 + w] = sqrtf(hs * hs + 1e-12f);
    } else {
        int w = col - 32;
        float gate = sigmoidf_(m[32 + w] * inv_c);
        float g0 = m[64 + 3 * w + 0] * inv_c * gate;
        float g1 = m[64 + 3 * w + 1] * inv_c * gate;
        float g2 = m[64 + 3 * w + 2] * inv_c * gate;
        float d0 = 0.f, d1 = 0.f, d2 = 0.f;
#pragma unroll 4
        for (int u = 0; u < 32; ++u) {
            float wv = Wsv[u * 32 + w];
            d0 += xp[32 + 3 * u + 0] * wv;
            d1 += xp[32 + 3 * u + 1] * wv;
            d2 += xp[32 + 3 * u + 2] * wv;
        }
        float h0 = g0 + d0 * IM, h1 = g1 + d1 * IM, h2 = g2 + d2 * IM;
        out[(size_t)n * 64 + 32 + w] = sqrtf(h0 * h0 + h1 * h1 + h2 * h2 + 1e-12f);
    }
}

extern "C" void kernel_launch(void* const* d_in, const int* in_sizes, int n_in,
                              void* d_out, int out_size, void* d_ws, size_t ws_size,
                              hipStream_t stream)
{
    const float* x    = (const float*)d_in[0];
    const float* ea   = (const float*)d_in[1];
    const float* elen = (const float*)d_in[2];
    const int*   esrc = (const int*)d_in[3];
    const int*   edst = (const int*)d_in[4];
    const float* W1   = (const float*)d_in[5];
    const float* W2   = (const float*)d_in[6];
    const float* Wss  = (const float*)d_in[7];
    const float* Wsv  = (const float*)d_in[8];
    float* out = (float*)d_out;

    const int N = in_sizes[0] / 128;   // 4096
    const int E = in_sizes[2];         // 32768

    // workspace layout (floats/ints)
    float* sums   = (float*)d_ws;                       // N*160
    float* cnt    = sums + (size_t)N * 160;             // N
    int*   histL  = (int*)(cnt + N);                    // 256
    int*   offL   = histL + 256;                        // 257
    int*   curL   = offL + 257;                         // 256
    int*   sortedL= curL + 256;                         // E
    float* hk     = (float*)(sortedL + E);              // NKNOT*64
    float* T      = hk + (size_t)NKNOT * 64;            // NKNOT*7168

    // zero sums + cnt + histL (contiguous)
    hipMemsetAsync(d_ws, 0, ((size_t)N * 161 + 256) * sizeof(float), stream);

    hk_kernel<<<(NKNOT * 64 + 255) / 256, 256, 0, stream>>>(W1, hk);
    table_kernel<<<dim3(7, (NKNOT + 7) / 8), 256, 0, stream>>>(hk, W2, T);
    hist_kernel<<<(E + 255) / 256, 256, 0, stream>>>(elen, histL, E);
    scan_kernel<<<1, 256, 0, stream>>>(histL, offL, curL);
    scatter_kernel<<<(E + 255) / 256, 256, 0, stream>>>(elen, curL, sortedL, E);
    fold_kernel<<<512, 256, 0, stream>>>(x, ea, elen, esrc, edst, offL, sortedL, T, sums, cnt);
    node_kernel<<<(N * 64 + 255) / 256, 256, 0, stream>>>(x, Wss, Wsv, sums, cnt, out, N);
}

// Round 4
// 412.085 us; speedup vs baseline: 4.1809x; 1.2735x over previous
//
#include <hip/hip_runtime.h>

#define NKNOT 257          // 256 intervals over [0,5]
#define KINV  51.2f        // 256/5
#define KSTEP 0.01953125f  // 5/256 (exact in fp32)
#define TPW   7168

__device__ __forceinline__ float sigmoidf_(float v) { return 1.f / (1.f + expf(-v)); }

// ---------------- h(L_k) knot table: hk[NKNOT][64] ----------------
__global__ void hk_kernel(const float* __restrict__ W1, float* __restrict__ hk)
{
    int idx = blockIdx.x * 256 + threadIdx.x;
    if (idx >= NKNOT * 64) return;
    int k = idx >> 6, c = idx & 63;
    float L = (float)k * KSTEP;
    float d = 0.f;
#pragma unroll
    for (int r = 0; r < 8; ++r) {
        float dd = L - (float)r * (5.f / 7.f);
        d += expf(-dd * dd * 0.98f) * W1[r * 64 + c];
    }
    d *= 0.3535533906f;                  // 1/sqrt(8)
    hk[idx] = d * sigmoidf_(d) * 0.125f; // silu, then 1/sqrt(64)
}

// ---------------- T[k][pw] = hk[k] @ W2 ----------------
__global__ __launch_bounds__(256)
void table_kernel(const float* __restrict__ hk, const float* __restrict__ W2,
                  float* __restrict__ T)
{
    int pw = blockIdx.x * 1024 + threadIdx.x * 4;
    int kt = blockIdx.y * 8;
    float4 acc[8];
#pragma unroll
    for (int q = 0; q < 8; ++q) acc[q] = make_float4(0.f, 0.f, 0.f, 0.f);
    for (int c = 0; c < 64; ++c) {
        float4 w4 = *(const float4*)(W2 + (size_t)c * TPW + pw);
#pragma unroll
        for (int q = 0; q < 8; ++q) {
            int kk = kt + q; kk = kk < NKNOT ? kk : NKNOT - 1;
            float hv = hk[kk * 64 + c];   // uniform -> scalar load
            acc[q].x = fmaf(hv, w4.x, acc[q].x);
            acc[q].y = fmaf(hv, w4.y, acc[q].y);
            acc[q].z = fmaf(hv, w4.z, acc[q].z);
            acc[q].w = fmaf(hv, w4.w, acc[q].w);
        }
    }
#pragma unroll
    for (int q = 0; q < 8; ++q)
        if (kt + q < NKNOT)
            *(float4*)(T + (size_t)(kt + q) * TPW + pw) = acc[q];
}

// ---------------- histograms: L-interval and dst ----------------
__global__ void hist_kernel(const float* __restrict__ elen, const int* __restrict__ edst,
                            int* __restrict__ histL, int* __restrict__ histD, int E)
{
    int e = blockIdx.x * 256 + threadIdx.x;
    if (e >= E) return;
    float t = elen[e] * KINV;
    int j = (int)t; j = j > 255 ? 255 : j;
    atomicAdd(&histL[j], 1);
    atomicAdd(&histD[edst[e]], 1);
}

// ---------------- scan of 256 (L) ----------------
__global__ void scanL_kernel(const int* __restrict__ histL, int* __restrict__ offL,
                             int* __restrict__ curL)
{
    __shared__ int sbuf[256];
    int t = threadIdx.x;
    int v = histL[t];
    sbuf[t] = v;
    __syncthreads();
    for (int d = 1; d < 256; d <<= 1) {
        int w = (t >= d) ? sbuf[t - d] : 0;
        __syncthreads();
        sbuf[t] += w;
        __syncthreads();
    }
    offL[t + 1] = sbuf[t];
    curL[t] = sbuf[t] - v;   // exclusive
    if (t == 0) offL[0] = 0;
}

// ---------------- scan of 4096 (dst), single block 1024 thr x 4 ----------------
__global__ __launch_bounds__(1024)
void scanD_kernel(const int* __restrict__ histD, int* __restrict__ offD,
                  int* __restrict__ curD, int N)
{
    __shared__ int sb[1024];
    int t = threadIdx.x;
    int base = t * 4;
    int v0 = histD[base], v1 = histD[base + 1], v2 = histD[base + 2], v3 = histD[base + 3];
    int l0 = v0, l1 = l0 + v1, l2 = l1 + v2, l3 = l2 + v3;
    sb[t] = l3;
    __syncthreads();
    for (int d = 1; d < 1024; d <<= 1) {
        int w = (t >= d) ? sb[t - d] : 0;
        __syncthreads();
        sb[t] += w;
        __syncthreads();
    }
    int gex = sb[t] - l3;   // exclusive group offset
    offD[base + 1] = gex + l0;
    offD[base + 2] = gex + l1;
    offD[base + 3] = gex + l2;
    offD[base + 4] = gex + l3;
    curD[base]     = gex;
    curD[base + 1] = gex + l0;
    curD[base + 2] = gex + l1;
    curD[base + 3] = gex + l2;
    if (t == 0) offD[0] = 0;
}

// ---------------- scatter by L (also records posL of each edge) ----------------
__global__ void scatterL_kernel(const float* __restrict__ elen, int* __restrict__ curL,
                                int* __restrict__ sortedL, int* __restrict__ posLof, int E)
{
    int e = blockIdx.x * 256 + threadIdx.x;
    if (e >= E) return;
    float t = elen[e] * KINV;
    int j = (int)t; j = j > 255 ? 255 : j;
    int pos = atomicAdd(&curL[j], 1);
    sortedL[pos] = e;
    posLof[e] = pos;
}

// ---------------- scatter by dst (stores L-sorted positions) ----------------
__global__ void scatterD_kernel(const int* __restrict__ edst, const int* __restrict__ posLof,
                                int* __restrict__ curD, int* __restrict__ sortedD, int E)
{
    int e = blockIdx.x * 256 + threadIdx.x;
    if (e >= E) return;
    int pos = atomicAdd(&curD[edst[e]], 1);
    sortedD[pos] = posLof[e];
}

// ---------------- main fold kernel: msg[posL][160], no atomics ----------------
__global__ __launch_bounds__(256, 2)
void fold_kernel(const float* __restrict__ x, const float* __restrict__ ea,
                 const float* __restrict__ elen, const int* __restrict__ esrc,
                 const int* __restrict__ offL, const int* __restrict__ sortedL,
                 const float* __restrict__ T, float* __restrict__ msg)
{
    const int j = blockIdx.x >> 1, half = blockIdx.x & 1;
    __shared__ float Tj[TPW];
    __shared__ float Tj1[TPW];
    __shared__ float EC[64][20];
    const int tid = threadIdx.x;

    // stage the two table rows
    const float* Trow = T + (size_t)j * TPW;
    for (int i = tid; i < TPW / 4; i += 256) {
        ((float4*)Tj)[i]  = ((const float4*)Trow)[i];
        ((float4*)Tj1)[i] = ((const float4*)(Trow + TPW))[i];
    }

    const int lo = offL[j], hi = offL[j + 1];
    const int nchunk = (hi - lo + 63) >> 6;
    const int slot = tid >> 3, wq = tid & 7;
    const float4* T4a = (const float4*)Tj;
    const float4* T4b = (const float4*)Tj1;
    const float I3 = 0.5773502692f, I5 = 0.4472135955f, S2 = 0.7071067812f;
    const float I6 = 0.4082482905f, T6 = 0.8164965809f;
    const float A0 = 0.125f, A1 = 0.1767766953f;

    for (int ci = half; ci < nchunk; ci += 2) {
        const int base = lo + (ci << 6);
        const int cntE = min(64, hi - base);
        __syncthreads();   // T ready (iter 0); EC free (later iters)
        if (tid < 64 && tid < cntE) {
            int e = sortedL[base + tid];
            float L = elen[e];
            float t = L * KINV;
            int jj = (int)t; jj = jj > 255 ? 255 : jj;
            EC[tid][0] = t - (float)jj;
            EC[tid][1] = __int_as_float(esrc[e]);
            const float* y = ea + (size_t)e * 9;
            float y0 = y[0];
            EC[tid][3] = y0;
            EC[tid][4] = y0 * I3;
            EC[tid][5] = y[1] * I3;
            EC[tid][6] = y[2] * I3;
            EC[tid][7] = y[3] * I3;
            float a = y[4], b = y[5], c = y[6], d2 = y[7], ee = y[8];
            EC[tid][8]  = (-c * I6 + ee * S2) * I5;
            EC[tid][9]  = a * S2 * I5;
            EC[tid][10] = d2 * S2 * I5;
            EC[tid][11] = a * S2 * I5;
            EC[tid][12] = (-c * I6 - ee * S2) * I5;
            EC[tid][13] = b * S2 * I5;
            EC[tid][14] = d2 * S2 * I5;
            EC[tid][15] = b * S2 * I5;
            EC[tid][16] = c * T6 * I5;
        }
        __syncthreads();

        const bool okA = slot < cntE;
        const bool okB = slot + 32 < cntE;
        float fA = EC[slot][0],      fB = EC[slot + 32][0];
        int srcA = okA ? __float_as_int(EC[slot][1]) : 0;
        int srcB = okB ? __float_as_int(EC[slot + 32][1]) : 0;
        float y0A = EC[slot][3],  y0iA = EC[slot][4];
        float y0B = EC[slot + 32][3], y0iB = EC[slot + 32][4];
        float y1iA[3] = { EC[slot][5], EC[slot][6], EC[slot][7] };
        float y1iB[3] = { EC[slot + 32][5], EC[slot + 32][6], EC[slot + 32][7] };
        float MA[9], MB[9];
#pragma unroll
        for (int q = 0; q < 9; ++q) { MA[q] = EC[slot][8 + q]; MB[q] = EC[slot + 32][8 + q]; }

        float accA[20], accB[20];
#pragma unroll
        for (int q = 0; q < 20; ++q) { accA[q] = 0.f; accB[q] = 0.f; }

        const float* xA = x + (size_t)srcA * 128;
        const float* xB = x + (size_t)srcB * 128;

#pragma unroll 1
        for (int uq = 0; uq < 8; ++uq) {
            float s4A[4], s4B[4], vvA[12], vvB[12];
            *(float4*)s4A = *(const float4*)(xA + (uq << 2));
            *(float4*)s4B = *(const float4*)(xB + (uq << 2));
            *(float4*)(vvA)     = *(const float4*)(xA + 32 + 12 * uq);
            *(float4*)(vvA + 4) = *(const float4*)(xA + 36 + 12 * uq);
            *(float4*)(vvA + 8) = *(const float4*)(xA + 40 + 12 * uq);
            *(float4*)(vvB)     = *(const float4*)(xB + 32 + 12 * uq);
            *(float4*)(vvB + 4) = *(const float4*)(xB + 36 + 12 * uq);
            *(float4*)(vvB + 8) = *(const float4*)(xB + 40 + 12 * uq);
#pragma unroll
            for (int up = 0; up < 4; ++up) {
                const int u = (uq << 2) + up;
                const float sA = s4A[up], sB = s4B[up];
                const float* vA_ = vvA + 3 * up;
                const float* vB_ = vvB + 3 * up;
                float t00A = sA * y0A;
                float t00B = sB * y0B;
                float t11A = vA_[0] * y1iA[0] + vA_[1] * y1iA[1] + vA_[2] * y1iA[2];
                float t11B = vB_[0] * y1iB[0] + vB_[1] * y1iB[1] + vB_[2] * y1iB[2];
                float t01A[3], t01B[3], t10A[3], t10B[3], t12A[3], t12B[3];
#pragma unroll
                for (int k = 0; k < 3; ++k) {
                    t01A[k] = sA * y1iA[k];
                    t01B[k] = sB * y1iB[k];
                    t10A[k] = vA_[k] * y0iA;
                    t10B[k] = vB_[k] * y0iB;
                    t12A[k] = vA_[0] * MA[k] + vA_[1] * MA[3 + k] + vA_[2] * MA[6 + k];
                    t12B[k] = vB_[0] * MB[k] + vB_[1] * MB[3 + k] + vB_[2] * MB[6 + k];
                }
                const int pw4 = (u << 3) + wq;
#pragma unroll
                for (int p = 0; p < 7; ++p) {
                    float4 Ta = T4a[(p << 8) + pw4];
                    float4 Tb = T4b[(p << 8) + pw4];
                    float d0 = Tb.x - Ta.x, d1 = Tb.y - Ta.y, d2_ = Tb.z - Ta.z, d3 = Tb.w - Ta.w;
                    float a0 = fmaf(fA, d0, Ta.x), a1 = fmaf(fA, d1, Ta.y);
                    float a2 = fmaf(fA, d2_, Ta.z), a3 = fmaf(fA, d3, Ta.w);
                    float b0 = fmaf(fB, d0, Ta.x), b1 = fmaf(fB, d1, Ta.y);
                    float b2 = fmaf(fB, d2_, Ta.z), b3 = fmaf(fB, d3, Ta.w);
                    if (p < 4) {
                        const int off = (p >> 1) << 2;   // 0 (S) or 4 (G)
                        float tA = (p & 1) ? t11A : t00A;
                        float tB = (p & 1) ? t11B : t00B;
                        accA[off + 0] = fmaf(tA, a0, accA[off + 0]);
                        accA[off + 1] = fmaf(tA, a1, accA[off + 1]);
                        accA[off + 2] = fmaf(tA, a2, accA[off + 2]);
                        accA[off + 3] = fmaf(tA, a3, accA[off + 3]);
                        accB[off + 0] = fmaf(tB, b0, accB[off + 0]);
                        accB[off + 1] = fmaf(tB, b1, accB[off + 1]);
                        accB[off + 2] = fmaf(tB, b2, accB[off + 2]);
                        accB[off + 3] = fmaf(tB, b3, accB[off + 3]);
                    } else {
#pragma unroll
                        for (int k = 0; k < 3; ++k) {
                            float tA = (p == 4) ? t01A[k] : (p == 5) ? t10A[k] : t12A[k];
                            float tB = (p == 4) ? t01B[k] : (p == 5) ? t10B[k] : t12B[k];
                            const int off = 8 + (k << 2);
                            accA[off + 0] = fmaf(tA, a0, accA[off + 0]);
                            accA[off + 1] = fmaf(tA, a1, accA[off + 1]);
                            accA[off + 2] = fmaf(tA, a2, accA[off + 2]);
                            accA[off + 3] = fmaf(tA, a3, accA[off + 3]);
                            accB[off + 0] = fmaf(tB, b0, accB[off + 0]);
                            accB[off + 1] = fmaf(tB, b1, accB[off + 1]);
                            accB[off + 2] = fmaf(tB, b2, accB[off + 2]);
                            accB[off + 3] = fmaf(tB, b3, accB[off + 3]);
                        }
                    }
                }
            }
        }

        // coalesced per-edge message stores (msg indexed by L-sorted position)
        const int wbase = wq << 2;
        if (okA) {
            float* mp = msg + (size_t)(base + slot) * 160;
            float4 sv = make_float4(accA[0] * A0, accA[1] * A0, accA[2] * A0, accA[3] * A0);
            float4 gv = make_float4(accA[4] * A0, accA[5] * A0, accA[6] * A0, accA[7] * A0);
            *(float4*)(mp + wbase)      = sv;
            *(float4*)(mp + 32 + wbase) = gv;
            float vb[12];
#pragma unroll
            for (int jj = 0; jj < 4; ++jj)
#pragma unroll
                for (int k = 0; k < 3; ++k)
                    vb[3 * jj + k] = accA[8 + (k << 2) + jj] * A1;
            *(float4*)(mp + 64 + 12 * wq)     = *(float4*)(vb);
            *(float4*)(mp + 64 + 12 * wq + 4) = *(float4*)(vb + 4);
            *(float4*)(mp + 64 + 12 * wq + 8) = *(float4*)(vb + 8);
        }
        if (okB) {
            float* mp = msg + (size_t)(base + slot + 32) * 160;
            float4 sv = make_float4(accB[0] * A0, accB[1] * A0, accB[2] * A0, accB[3] * A0);
            float4 gv = make_float4(accB[4] * A0, accB[5] * A0, accB[6] * A0, accB[7] * A0);
            *(float4*)(mp + wbase)      = sv;
            *(float4*)(mp + 32 + wbase) = gv;
            float vb[12];
#pragma unroll
            for (int jj = 0; jj < 4; ++jj)
#pragma unroll
                for (int k = 0; k < 3; ++k)
                    vb[3 * jj + k] = accB[8 + (k << 2) + jj] * A1;
            *(float4*)(mp + 64 + 12 * wq)     = *(float4*)(vb);
            *(float4*)(mp + 64 + 12 * wq + 4) = *(float4*)(vb + 4);
            *(float4*)(mp + 64 + 12 * wq + 8) = *(float4*)(vb + 8);
        }
    }
}

// ---------------- gather: m[n][c] = mean over dst-edges of msg ----------------
__global__ __launch_bounds__(256)
void gather_kernel(const float* __restrict__ msg, const int* __restrict__ sortedD,
                   const int* __restrict__ offD, float* __restrict__ m, int N)
{
    int tid = blockIdx.x * 256 + threadIdx.x;
    int n = tid / 160;
    int c = tid - n * 160;
    if (n >= N) return;
    int lo = offD[n], hi = offD[n + 1];
    float s = 0.f;
    for (int i = lo; i < hi; ++i) {
        int p = sortedD[i];
        s += msg[(size_t)p * 160 + c];
    }
    float inv = 1.f / fmaxf((float)(hi - lo), 1.f);
    m[(size_t)n * 160 + c] = s * inv;
}

// ---------------- per-node epilogue ----------------
__global__ __launch_bounds__(256)
void node_kernel(const float* __restrict__ x, const float* __restrict__ Wss,
                 const float* __restrict__ Wsv, const float* __restrict__ m_,
                 float* __restrict__ out, int N)
{
    int t = blockIdx.x * 256 + threadIdx.x;
    int n = t >> 6, col = t & 63;
    if (n >= N) return;
    const float* m  = m_ + (size_t)n * 160;
    const float* xp = x + (size_t)n * 128;
    const float IM = 0.1767766953f;  // 1/sqrt(32)
    if (col < 32) {
        int w = col;
        float ms = m[w];
        float gs = ms * sigmoidf_(ms);
        float dot = 0.f;
#pragma unroll 4
        for (int u = 0; u < 32; ++u) dot += xp[u] * Wss[u * 32 + w];
        float hs = gs + dot * IM;
        out[(size_t)n * 64 + w] = sqrtf(hs * hs + 1e-12f);
    } else {
        int w = col - 32;
        float gate = sigmoidf_(m[32 + w]);
        float g0 = m[64 + 3 * w + 0] * gate;
        float g1 = m[64 + 3 * w + 1] * gate;
        float g2 = m[64 + 3 * w + 2] * gate;
        float d0 = 0.f, d1 = 0.f, d2 = 0.f;
#pragma unroll 4
        for (int u = 0; u < 32; ++u) {
            float wv = Wsv[u * 32 + w];
            d0 += xp[32 + 3 * u + 0] * wv;
            d1 += xp[32 + 3 * u + 1] * wv;
            d2 += xp[32 + 3 * u + 2] * wv;
        }
        float h0 = g0 + d0 * IM, h1 = g1 + d1 * IM, h2 = g2 + d2 * IM;
        out[(size_t)n * 64 + 32 + w] = sqrtf(h0 * h0 + h1 * h1 + h2 * h2 + 1e-12f);
    }
}

extern "C" void kernel_launch(void* const* d_in, const int* in_sizes, int n_in,
                              void* d_out, int out_size, void* d_ws, size_t ws_size,
                              hipStream_t stream)
{
    const float* x    = (const float*)d_in[0];
    const float* ea   = (const float*)d_in[1];
    const float* elen = (const float*)d_in[2];
    const int*   esrc = (const int*)d_in[3];
    const int*   edst = (const int*)d_in[4];
    const float* W1   = (const float*)d_in[5];
    const float* W2   = (const float*)d_in[6];
    const float* Wss  = (const float*)d_in[7];
    const float* Wsv  = (const float*)d_in[8];
    float* out = (float*)d_out;

    const int N = in_sizes[0] / 128;   // 4096
    const int E = in_sizes[2];         // 32768

    // workspace layout
    float* m      = (float*)d_ws;                       // N*160
    int*   histL  = (int*)(m + (size_t)N * 160);        // 256
    int*   histD  = histL + 256;                        // N (4096)  [contig w/ histL for memset]
    int*   offL   = histD + N;                          // 257
    int*   curL   = offL + 257;                         // 256
    int*   offD   = curL + 256;                         // N+1
    int*   curD   = offD + N + 1;                       // N
    int*   sortedL= curD + N;                           // E
    int*   posLof = sortedL + E;                        // E
    int*   sortedD= posLof + E;                         // E
    float* hk     = (float*)(sortedD + E);              // NKNOT*64
    float* T      = hk + (size_t)NKNOT * 64;            // NKNOT*7168
    float* msg    = T + (size_t)NKNOT * TPW;            // E*160

    // zero the two histograms (contiguous)
    hipMemsetAsync(histL, 0, (size_t)(256 + N) * sizeof(int), stream);

    hk_kernel<<<(NKNOT * 64 + 255) / 256, 256, 0, stream>>>(W1, hk);
    table_kernel<<<dim3(7, (NKNOT + 7) / 8), 256, 0, stream>>>(hk, W2, T);
    hist_kernel<<<(E + 255) / 256, 256, 0, stream>>>(elen, edst, histL, histD, E);
    scanL_kernel<<<1, 256, 0, stream>>>(histL, offL, curL);
    scanD_kernel<<<1, 1024, 0, stream>>>(histD, offD, curD, N);
    scatterL_kernel<<<(E + 255) / 256, 256, 0, stream>>>(elen, curL, sortedL, posLof, E);
    scatterD_kernel<<<(E + 255) / 256, 256, 0, stream>>>(edst, posLof, curD, sortedD, E);
    fold_kernel<<<512, 256, 0, stream>>>(x, ea, elen, esrc, offL, sortedL, T, msg);
    gather_kernel<<<(N * 160 + 255) / 256, 256, 0, stream>>>(msg, sortedD, offD, m, N);
    node_kernel<<<(N * 64 + 255) / 256, 256, 0, stream>>>(x, Wss, Wsv, m, out, N);
}

// Round 5
// 209.481 us; speedup vs baseline: 8.2245x; 1.9672x over previous
//
#include <hip/hip_runtime.h>

#define NKNOT 257          // 256 intervals over [0,5]
#define KINV  51.2f        // 256/5
#define KSTEP 0.01953125f  // 5/256 (exact in fp32)
#define TPW   7168

__device__ __forceinline__ float sigmoidf_(float v) { return 1.f / (1.f + expf(-v)); }

// ---------------- h(L_k) knot table: hk[NKNOT][64] ----------------
__global__ void hk_kernel(const float* __restrict__ W1, float* __restrict__ hk)
{
    int idx = blockIdx.x * 256 + threadIdx.x;
    if (idx >= NKNOT * 64) return;
    int k = idx >> 6, c = idx & 63;
    float L = (float)k * KSTEP;
    float d = 0.f;
#pragma unroll
    for (int r = 0; r < 8; ++r) {
        float dd = L - (float)r * (5.f / 7.f);
        d += expf(-dd * dd * 0.98f) * W1[r * 64 + c];
    }
    d *= 0.3535533906f;                  // 1/sqrt(8)
    hk[idx] = d * sigmoidf_(d) * 0.125f; // silu, then 1/sqrt(64)
}

// ---------------- T[k][pw] = hk[k] @ W2 ----------------
__global__ __launch_bounds__(256)
void table_kernel(const float* __restrict__ hk, const float* __restrict__ W2,
                  float* __restrict__ T)
{
    int pw = blockIdx.x * 1024 + threadIdx.x * 4;
    int kt = blockIdx.y * 8;
    float4 acc[8];
#pragma unroll
    for (int q = 0; q < 8; ++q) acc[q] = make_float4(0.f, 0.f, 0.f, 0.f);
    for (int c = 0; c < 64; ++c) {
        float4 w4 = *(const float4*)(W2 + (size_t)c * TPW + pw);
#pragma unroll
        for (int q = 0; q < 8; ++q) {
            int kk = kt + q; kk = kk < NKNOT ? kk : NKNOT - 1;
            float hv = hk[kk * 64 + c];   // uniform -> scalar load
            acc[q].x = fmaf(hv, w4.x, acc[q].x);
            acc[q].y = fmaf(hv, w4.y, acc[q].y);
            acc[q].z = fmaf(hv, w4.z, acc[q].z);
            acc[q].w = fmaf(hv, w4.w, acc[q].w);
        }
    }
#pragma unroll
    for (int q = 0; q < 8; ++q)
        if (kt + q < NKNOT)
            *(float4*)(T + (size_t)(kt + q) * TPW + pw) = acc[q];
}

// ---------------- histograms: L-interval and dst ----------------
__global__ void hist_kernel(const float* __restrict__ elen, const int* __restrict__ edst,
                            int* __restrict__ histL, int* __restrict__ histD, int E)
{
    int e = blockIdx.x * 256 + threadIdx.x;
    if (e >= E) return;
    float t = elen[e] * KINV;
    int j = (int)t; j = j > 255 ? 255 : j;
    atomicAdd(&histL[j], 1);
    atomicAdd(&histD[edst[e]], 1);
}

// ---------------- scan of 256 (L) ----------------
__global__ void scanL_kernel(const int* __restrict__ histL, int* __restrict__ offL,
                             int* __restrict__ curL)
{
    __shared__ int sbuf[256];
    int t = threadIdx.x;
    int v = histL[t];
    sbuf[t] = v;
    __syncthreads();
    for (int d = 1; d < 256; d <<= 1) {
        int w = (t >= d) ? sbuf[t - d] : 0;
        __syncthreads();
        sbuf[t] += w;
        __syncthreads();
    }
    offL[t + 1] = sbuf[t];
    curL[t] = sbuf[t] - v;   // exclusive
    if (t == 0) offL[0] = 0;
}

// ---------------- scan of 4096 (dst), single block 1024 thr x 4 ----------------
__global__ __launch_bounds__(1024)
void scanD_kernel(const int* __restrict__ histD, int* __restrict__ offD,
                  int* __restrict__ curD, int N)
{
    __shared__ int sb[1024];
    int t = threadIdx.x;
    int base = t * 4;
    int v0 = histD[base], v1 = histD[base + 1], v2 = histD[base + 2], v3 = histD[base + 3];
    int l0 = v0, l1 = l0 + v1, l2 = l1 + v2, l3 = l2 + v3;
    sb[t] = l3;
    __syncthreads();
    for (int d = 1; d < 1024; d <<= 1) {
        int w = (t >= d) ? sb[t - d] : 0;
        __syncthreads();
        sb[t] += w;
        __syncthreads();
    }
    int gex = sb[t] - l3;   // exclusive group offset
    offD[base + 1] = gex + l0;
    offD[base + 2] = gex + l1;
    offD[base + 3] = gex + l2;
    offD[base + 4] = gex + l3;
    curD[base]     = gex;
    curD[base + 1] = gex + l0;
    curD[base + 2] = gex + l1;
    curD[base + 3] = gex + l2;
    if (t == 0) offD[0] = 0;
}

// ---------------- scatter by L (also records posL of each edge) ----------------
__global__ void scatterL_kernel(const float* __restrict__ elen, int* __restrict__ curL,
                                int* __restrict__ sortedL, int* __restrict__ posLof, int E)
{
    int e = blockIdx.x * 256 + threadIdx.x;
    if (e >= E) return;
    float t = elen[e] * KINV;
    int j = (int)t; j = j > 255 ? 255 : j;
    int pos = atomicAdd(&curL[j], 1);
    sortedL[pos] = e;
    posLof[e] = pos;
}

// ---------------- scatter by dst (stores L-sorted positions) ----------------
__global__ void scatterD_kernel(const int* __restrict__ edst, const int* __restrict__ posLof,
                                int* __restrict__ curD, int* __restrict__ sortedD, int E)
{
    int e = blockIdx.x * 256 + threadIdx.x;
    if (e >= E) return;
    int pos = atomicAdd(&curD[edst[e]], 1);
    sortedD[pos] = posLof[e];
}

// ---------------- main fold kernel: one edge per slot, no spills ----------------
// chunk = 32 edges; 256 threads = 32 slots x 8 w-quads. acc[20]/thread.
// LDS holds T[j] and D = T[j+1]-T[j]; message = Ta + f*D folded with t.
__global__ __launch_bounds__(256, 2)
void fold_kernel(const float* __restrict__ x, const float* __restrict__ ea,
                 const float* __restrict__ elen, const int* __restrict__ esrc,
                 const int* __restrict__ offL, const int* __restrict__ sortedL,
                 const float* __restrict__ T, float* __restrict__ msg)
{
    const int j = blockIdx.x >> 1, half = blockIdx.x & 1;
    __shared__ float Ta_s[TPW];
    __shared__ float D_s[TPW];
    __shared__ float EC[32][20];
    const int tid = threadIdx.x;

    // stage T[j] and the knot difference
    const float* Trow = T + (size_t)j * TPW;
    for (int i = tid; i < TPW / 4; i += 256) {
        float4 a = ((const float4*)Trow)[i];
        float4 b = ((const float4*)(Trow + TPW))[i];
        ((float4*)Ta_s)[i] = a;
        ((float4*)D_s)[i]  = make_float4(b.x - a.x, b.y - a.y, b.z - a.z, b.w - a.w);
    }

    const int lo = offL[j], hi = offL[j + 1];
    const int nchunk = (hi - lo + 31) >> 5;
    const int slot = tid >> 3, wq = tid & 7;
    const float4* T4a = (const float4*)Ta_s;
    const float4* D4  = (const float4*)D_s;
    const float I3 = 0.5773502692f, I5 = 0.4472135955f, S2 = 0.7071067812f;
    const float I6 = 0.4082482905f, T6 = 0.8164965809f;
    const float A0 = 0.125f, A1 = 0.1767766953f;

    for (int ci = half; ci < nchunk; ci += 2) {
        const int base = lo + (ci << 5);
        const int cntE = min(32, hi - base);
        __syncthreads();   // T ready (iter 0); EC free (later iters)
        if (tid < 32 && tid < cntE) {
            int e = sortedL[base + tid];
            float L = elen[e];
            float t = L * KINV;
            int jj = (int)t; jj = jj > 255 ? 255 : jj;
            EC[tid][0] = t - (float)jj;
            EC[tid][1] = __int_as_float(esrc[e]);
            const float* y = ea + (size_t)e * 9;
            float y0 = y[0];
            EC[tid][3] = y0;
            EC[tid][4] = y0 * I3;
            EC[tid][5] = y[1] * I3;
            EC[tid][6] = y[2] * I3;
            EC[tid][7] = y[3] * I3;
            float a = y[4], b = y[5], c = y[6], d2 = y[7], ee = y[8];
            EC[tid][8]  = (-c * I6 + ee * S2) * I5;
            EC[tid][9]  = a * S2 * I5;
            EC[tid][10] = d2 * S2 * I5;
            EC[tid][11] = a * S2 * I5;
            EC[tid][12] = (-c * I6 - ee * S2) * I5;
            EC[tid][13] = b * S2 * I5;
            EC[tid][14] = d2 * S2 * I5;
            EC[tid][15] = b * S2 * I5;
            EC[tid][16] = c * T6 * I5;
        }
        __syncthreads();

        const bool ok = slot < cntE;
        float f  = EC[slot][0];
        int  src = ok ? __float_as_int(EC[slot][1]) : 0;
        float y0  = EC[slot][3], y0i = EC[slot][4];
        float y1i[3] = { EC[slot][5], EC[slot][6], EC[slot][7] };
        float M[9];
#pragma unroll
        for (int q = 0; q < 9; ++q) M[q] = EC[slot][8 + q];

        float acc[20];
#pragma unroll
        for (int q = 0; q < 20; ++q) acc[q] = 0.f;

        const float* xp = x + (size_t)src * 128;

#pragma unroll 1
        for (int uq = 0; uq < 8; ++uq) {
            float s4[4], vv[12];
            *(float4*)s4 = *(const float4*)(xp + (uq << 2));
            *(float4*)(vv)     = *(const float4*)(xp + 32 + 12 * uq);
            *(float4*)(vv + 4) = *(const float4*)(xp + 36 + 12 * uq);
            *(float4*)(vv + 8) = *(const float4*)(xp + 40 + 12 * uq);
#pragma unroll
            for (int up = 0; up < 4; ++up) {
                const int u = (uq << 2) + up;
                const float s = s4[up];
                const float* v_ = vv + 3 * up;
                float t00 = s * y0;
                float t11 = v_[0] * y1i[0] + v_[1] * y1i[1] + v_[2] * y1i[2];
                float t01[3], t10[3], t12[3];
#pragma unroll
                for (int k = 0; k < 3; ++k) {
                    t01[k] = s * y1i[k];
                    t10[k] = v_[k] * y0i;
                    t12[k] = v_[0] * M[k] + v_[1] * M[3 + k] + v_[2] * M[6 + k];
                }
                const int pw4 = (u << 3) + wq;
#pragma unroll
                for (int p = 0; p < 7; ++p) {
                    float4 Ta = T4a[(p << 8) + pw4];
                    float4 Dv = D4[(p << 8) + pw4];
                    float w0 = fmaf(f, Dv.x, Ta.x);
                    float w1 = fmaf(f, Dv.y, Ta.y);
                    float w2 = fmaf(f, Dv.z, Ta.z);
                    float w3 = fmaf(f, Dv.w, Ta.w);
                    if (p < 4) {
                        const int off = (p >> 1) << 2;   // 0 (S) or 4 (G)
                        float t = (p & 1) ? t11 : t00;
                        acc[off + 0] = fmaf(t, w0, acc[off + 0]);
                        acc[off + 1] = fmaf(t, w1, acc[off + 1]);
                        acc[off + 2] = fmaf(t, w2, acc[off + 2]);
                        acc[off + 3] = fmaf(t, w3, acc[off + 3]);
                    } else {
#pragma unroll
                        for (int k = 0; k < 3; ++k) {
                            float t = (p == 4) ? t01[k] : (p == 5) ? t10[k] : t12[k];
                            const int off = 8 + (k << 2);
                            acc[off + 0] = fmaf(t, w0, acc[off + 0]);
                            acc[off + 1] = fmaf(t, w1, acc[off + 1]);
                            acc[off + 2] = fmaf(t, w2, acc[off + 2]);
                            acc[off + 3] = fmaf(t, w3, acc[off + 3]);
                        }
                    }
                }
            }
        }

        // coalesced per-edge message stores (msg indexed by L-sorted position)
        if (ok) {
            const int wbase = wq << 2;
            float* mp = msg + (size_t)(base + slot) * 160;
            float4 sv = make_float4(acc[0] * A0, acc[1] * A0, acc[2] * A0, acc[3] * A0);
            float4 gv = make_float4(acc[4] * A0, acc[5] * A0, acc[6] * A0, acc[7] * A0);
            *(float4*)(mp + wbase)      = sv;
            *(float4*)(mp + 32 + wbase) = gv;
            float vb[12];
#pragma unroll
            for (int jj = 0; jj < 4; ++jj)
#pragma unroll
                for (int k = 0; k < 3; ++k)
                    vb[3 * jj + k] = acc[8 + (k << 2) + jj] * A1;
            *(float4*)(mp + 64 + 12 * wq)     = *(float4*)(vb);
            *(float4*)(mp + 64 + 12 * wq + 4) = *(float4*)(vb + 4);
            *(float4*)(mp + 64 + 12 * wq + 8) = *(float4*)(vb + 8);
        }
    }
}

// ---------------- gather: m[n][c] = mean over dst-edges of msg ----------------
__global__ __launch_bounds__(256)
void gather_kernel(const float* __restrict__ msg, const int* __restrict__ sortedD,
                   const int* __restrict__ offD, float* __restrict__ m, int N)
{
    int tid = blockIdx.x * 256 + threadIdx.x;
    int n = tid / 160;
    int c = tid - n * 160;
    if (n >= N) return;
    int lo = offD[n], hi = offD[n + 1];
    float s = 0.f;
    for (int i = lo; i < hi; ++i) {
        int p = sortedD[i];
        s += msg[(size_t)p * 160 + c];
    }
    float inv = 1.f / fmaxf((float)(hi - lo), 1.f);
    m[(size_t)n * 160 + c] = s * inv;
}

// ---------------- per-node epilogue ----------------
__global__ __launch_bounds__(256)
void node_kernel(const float* __restrict__ x, const float* __restrict__ Wss,
                 const float* __restrict__ Wsv, const float* __restrict__ m_,
                 float* __restrict__ out, int N)
{
    int t = blockIdx.x * 256 + threadIdx.x;
    int n = t >> 6, col = t & 63;
    if (n >= N) return;
    const float* m  = m_ + (size_t)n * 160;
    const float* xp = x + (size_t)n * 128;
    const float IM = 0.1767766953f;  // 1/sqrt(32)
    if (col < 32) {
        int w = col;
        float ms = m[w];
        float gs = ms * sigmoidf_(ms);
        float dot = 0.f;
#pragma unroll 4
        for (int u = 0; u < 32; ++u) dot += xp[u] * Wss[u * 32 + w];
        float hs = gs + dot * IM;
        out[(size_t)n * 64 + w] = sqrtf(hs * hs + 1e-12f);
    } else {
        int w = col - 32;
        float gate = sigmoidf_(m[32 + w]);
        float g0 = m[64 + 3 * w + 0] * gate;
        float g1 = m[64 + 3 * w + 1] * gate;
        float g2 = m[64 + 3 * w + 2] * gate;
        float d0 = 0.f, d1 = 0.f, d2 = 0.f;
#pragma unroll 4
        for (int u = 0; u < 32; ++u) {
            float wv = Wsv[u * 32 + w];
            d0 += xp[32 + 3 * u + 0] * wv;
            d1 += xp[32 + 3 * u + 1] * wv;
            d2 += xp[32 + 3 * u + 2] * wv;
        }
        float h0 = g0 + d0 * IM, h1 = g1 + d1 * IM, h2 = g2 + d2 * IM;
        out[(size_t)n * 64 + 32 + w] = sqrtf(h0 * h0 + h1 * h1 + h2 * h2 + 1e-12f);
    }
}

extern "C" void kernel_launch(void* const* d_in, const int* in_sizes, int n_in,
                              void* d_out, int out_size, void* d_ws, size_t ws_size,
                              hipStream_t stream)
{
    const float* x    = (const float*)d_in[0];
    const float* ea   = (const float*)d_in[1];
    const float* elen = (const float*)d_in[2];
    const int*   esrc = (const int*)d_in[3];
    const int*   edst = (const int*)d_in[4];
    const float* W1   = (const float*)d_in[5];
    const float* W2   = (const float*)d_in[6];
    const float* Wss  = (const float*)d_in[7];
    const float* Wsv  = (const float*)d_in[8];
    float* out = (float*)d_out;

    const int N = in_sizes[0] / 128;   // 4096
    const int E = in_sizes[2];         // 32768

    // workspace layout
    float* m      = (float*)d_ws;                       // N*160
    int*   histL  = (int*)(m + (size_t)N * 160);        // 256
    int*   histD  = histL + 256;                        // N (4096)  [contig w/ histL for memset]
    int*   offL   = histD + N;                          // 257
    int*   curL   = offL + 257;                         // 256
    int*   offD   = curL + 256;                         // N+1
    int*   curD   = offD + N + 1;                       // N
    int*   sortedL= curD + N;                           // E
    int*   posLof = sortedL + E;                        // E
    int*   sortedD= posLof + E;                         // E
    float* hk     = (float*)(sortedD + E);              // NKNOT*64
    float* T      = hk + (size_t)NKNOT * 64;            // NKNOT*7168
    float* msg    = T + (size_t)NKNOT * TPW;            // E*160

    // zero the two histograms (contiguous)
    hipMemsetAsync(histL, 0, (size_t)(256 + N) * sizeof(int), stream);

    hk_kernel<<<(NKNOT * 64 + 255) / 256, 256, 0, stream>>>(W1, hk);
    table_kernel<<<dim3(7, (NKNOT + 7) / 8), 256, 0, stream>>>(hk, W2, T);
    hist_kernel<<<(E + 255) / 256, 256, 0, stream>>>(elen, edst, histL, histD, E);
    scanL_kernel<<<1, 256, 0, stream>>>(histL, offL, curL);
    scanD_kernel<<<1, 1024, 0, stream>>>(histD, offD, curD, N);
    scatterL_kernel<<<(E + 255) / 256, 256, 0, stream>>>(elen, curL, sortedL, posLof, E);
    scatterD_kernel<<<(E + 255) / 256, 256, 0, stream>>>(edst, posLof, curD, sortedD, E);
    fold_kernel<<<512, 256, 0, stream>>>(x, ea, elen, esrc, offL, sortedL, T, msg);
    gather_kernel<<<(N * 160 + 255) / 256, 256, 0, stream>>>(msg, sortedD, offD, m, N);
    node_kernel<<<(N * 64 + 255) / 256, 256, 0, stream>>>(x, Wss, Wsv, m, out, N);
}